// Round 1
// baseline (2491.518 us; speedup 1.0000x reference)
//
#include <hip/hip_runtime.h>
#include <math.h>

#define NIMG 12
#define NSZ 256
#define HWSZ 65536

// ---------------- 256-point Stockham FFT, one wave (64 lanes) per transform ---------------
// A/B: per-transform 256-float2 LDS slices. tw[t] = (cos(2pi t/256), sin(2pi t/256)).
// dir = -1 forward, +1 inverse (unnormalized). Result ends in A. Uniform control flow required.
__device__ __forceinline__ void fft256(float2* A, float2* B, const float2* tw, int lane, float dir)
{
  float2* src = A;
  float2* dst = B;
  int m = 1;
#pragma unroll
  for (int s = 0; s < 8; ++s) {
    __syncthreads();
#pragma unroll
    for (int h = 0; h < 2; ++h) {
      int b = lane + (h << 6);          // butterfly id 0..127
      int k = b & (m - 1);
      int jm = b - k;                   // j*m, twiddle index
      float2 a = src[b];
      float2 c = src[b + 128];
      float2 w = tw[jm];
      float wr = w.x, wi = dir * w.y;
      float ex = a.x - c.x, ey = a.y - c.y;
      dst[2 * jm + k]     = make_float2(a.x + c.x, a.y + c.y);
      dst[2 * jm + k + m] = make_float2(ex * wr - ey * wi, ex * wi + ey * wr);
    }
    float2* t = src; src = dst; dst = t;
    m <<= 1;
  }
  __syncthreads();
}

__device__ __forceinline__ void make_tw(float2* tw, int t)
{
  float s, c;
  sincospif((float)t * (1.0f / 128.0f), &s, &c);   // angle = 2*pi*t/256, exact argument
  tw[t] = make_float2(c, s);
}

// fd(k) = |1 - exp(-2pi i k/256)|^2 = 2 - 2cos(2pi k /256)
__device__ __forceinline__ double fdval(const float2* tw, int k)
{
  return 2.0 - 2.0 * (double)tw[k].x;
}

// ---------------- S1: row forward FFT of real STy -> W ----------------
__global__ __launch_bounds__(256) void k_rowfwd_sty(const float* __restrict__ sty,
                                                    float2* __restrict__ Wb)
{
  __shared__ float2 tw[256];
  __shared__ float2 bufA[4][256];
  __shared__ float2 bufB[4][256];
  int t = threadIdx.x;
  make_tw(tw, t);
  int n = blockIdx.x >> 6;
  int r0 = (blockIdx.x & 63) << 2;
  int w = t >> 6, lane = t & 63;
  const float* src = sty + (size_t)n * HWSZ + (size_t)(r0 + w) * NSZ;
#pragma unroll
  for (int q = 0; q < 4; ++q) { int j = lane + (q << 6); bufA[w][j] = make_float2(src[j], 0.f); }
  fft256(bufA[w], bufB[w], tw, lane, -1.f);
  float2* dst = Wb + (size_t)n * HWSZ + (size_t)(r0 + w) * NSZ;
#pragma unroll
  for (int q = 0; q < 4; ++q) { int j = lane + (q << 6); dst[j] = bufA[w][j]; }
}

// ---------------- S2: column fwd FFT of W -> FSTy; store FkFSTy, den; Fr0; column inv FFT -> W
// block owns columns {j0, j0+1, j0+128, j0+129} of image n  (j0 even)
__global__ __launch_bounds__(256) void k_colsetup(float2* __restrict__ Wb,
                                                  float2* __restrict__ FkF,
                                                  const float* __restrict__ fkr,
                                                  const float* __restrict__ fki,
                                                  float* __restrict__ denq)
{
  __shared__ float2 tw[256];
  __shared__ float2 bufA[4][256];
  __shared__ float2 bufB[4][256];
  __shared__ float dsA[2][128];
  int t = threadIdx.x;
  make_tw(tw, t);
  int n = blockIdx.x >> 6;
  int j0 = (blockIdx.x & 63) << 1;
  int w = t >> 6, lane = t & 63;
  int gcw = j0 + (w & 1) + ((w >> 1) << 7);
  float2* Wn = Wb + (size_t)n * HWSZ;
#pragma unroll
  for (int q = 0; q < 4; ++q) { int u = lane + (q << 6); bufA[w][u] = Wn[(size_t)u * NSZ + gcw]; }
  fft256(bufA[w], bufB[w], tw, lane, -1.f);     // bufA = FSTy columns
  // FkFSTy = conj(Fk)*FSTy (store + keep in LDS)
#pragma unroll
  for (int c = 0; c < 4; ++c) {
    int u = t;
    int gc = j0 + (c & 1) + ((c >> 1) << 7);
    size_t idx = (size_t)n * HWSZ + (size_t)u * NSZ + gc;
    float kr = fkr[idx], ki = fki[idx];
    float2 f = bufA[c][u];
    float2 kf = make_float2(kr * f.x + ki * f.y, kr * f.y - ki * f.x);
    FkF[idx] = kf;
    bufA[c][u] = kf;
  }
  __syncthreads();
  // block-local freq_downsample reductions: den = ds(Fk2/FD2)+alpha ; dsA = ds(Fk2)+alpha
  {
    int u0 = t & 127, p = t >> 7;
    double s1 = 0.0, s2 = 0.0;
#pragma unroll
    for (int s = 0; s < 4; ++s) {
      int u = u0 + ((s & 1) << 7);
      int c = p + ((s >> 1) << 1);
      int gc = j0 + (c & 1) + ((c >> 1) << 7);
      size_t idx = (size_t)n * HWSZ + (size_t)u * NSZ + gc;
      double kr = fkr[idx], ki = fki[idx];
      double k2 = kr * kr + ki * ki;
      double fd2 = fdval(tw, u) + fdval(tw, gc) + 1e-8;
      s1 += k2;
      s2 += k2 / fd2;
    }
    denq[(size_t)n * 16384 + (size_t)u0 * 128 + (j0 + p)] = (float)(s2 * 0.25 + 1e-6);
    dsA[p][u0] = (float)(s1 * 0.25 + 1e-6);
  }
  __syncthreads();
  // Fr0 = FkFSTy / dsA(tiled)
#pragma unroll
  for (int c = 0; c < 4; ++c) {
    int u = t;
    float d = dsA[c & 1][u & 127];
    float2 kf = bufA[c][u];
    bufA[c][u] = make_float2(kf.x / d, kf.y / d);
  }
  fft256(bufA[w], bufB[w], tw, lane, +1.f);     // inverse along columns (unnormalized)
#pragma unroll
  for (int q = 0; q < 4; ++q) { int u = lane + (q << 6); Wn[(size_t)u * NSZ + gcw] = bufA[w][u]; }
}

// ---------------- K41: shrinkage(iter k entry state) + G + row forward FFT -> W -------------
// block owns rows r0..r0+3 of image n; recomputes shrink for halo row r0+4.
__global__ __launch_bounds__(256) void k_spatial_rowfwd(const float* __restrict__ x,
                                                        const float* __restrict__ D1p,
                                                        const float* __restrict__ D2p,
                                                        float* __restrict__ D1n,
                                                        float* __restrict__ D2n,
                                                        float2* __restrict__ Wb,
                                                        float gamp, int firstIter)
{
  __shared__ float2 tw[256];
  __shared__ float aL[5][256];
  __shared__ float bL[5][256];
  __shared__ float2 bufA[4][256];
  __shared__ float2 bufB[4][256];
  int t = threadIdx.x;
  make_tw(tw, t);
  int n = blockIdx.x >> 6;
  int r0 = (blockIdx.x & 63) << 2;
  const float* xn = x + (size_t)n * HWSZ;
  // pass A: (U - D) for rows r0..r0+4 ; write new D for own rows
  for (int rr = 0; rr < 5; ++rr) {
    int i = (r0 + rr) & 255;
    int im1 = (i - 1) & 255;
    int j = t;
    int jm1 = (j - 1) & 255;
    float xc = xn[(size_t)i * NSZ + j];
    float a, b;
    if (firstIter) {
      a = xc; b = xc;                      // U=x0, D=0
    } else {
      float dhr = xc - xn[(size_t)i * NSZ + jm1];
      float dvr = xc - xn[(size_t)im1 * NSZ + j];
      size_t idx = (size_t)n * HWSZ + (size_t)i * NSZ + j;
      float d1 = D1p[idx], d2 = D2p[idx];
      float nu1 = dhr + d1, nu2 = dvr + d2;
      float nu = sqrtf(nu1 * nu1 + nu2 * nu2 + 1e-8f);
      float A = fmaxf(0.f, nu - gamp) + 1e-8f;
      A = A / (A + gamp);
      float u1 = A * nu1, u2 = A * nu2;
      float d1v = d1 + dhr - u1;
      float d2v = d2 + dvr - u2;
      if (rr < 4) { D1n[idx] = d1v; D2n[idx] = d2v; }
      a = u1 - d1v; b = u2 - d2v;
    }
    aL[rr][j] = a;
    bL[rr][j] = b;
  }
  __syncthreads();
  int w = t >> 6, lane = t & 63;
  // pass B: G = adjdiff_h(a) + adjdiff_v(b), then row FFT
#pragma unroll
  for (int q = 0; q < 4; ++q) {
    int j = lane + (q << 6);
    int jp1 = (j + 1) & 255;
    float g = aL[w][j] - aL[w][jp1] + bL[w][j] - bL[w + 1][j];
    bufA[w][j] = make_float2(g, 0.f);
  }
  fft256(bufA[w], bufB[w], tw, lane, -1.f);
  float2* dst = Wb + (size_t)n * HWSZ + (size_t)(r0 + w) * NSZ;
#pragma unroll
  for (int q = 0; q < 4; ++q) { int j = lane + (q << 6); dst[j] = bufA[w][j]; }
}

// ---------------- K2: column fwd FFT + frequency pointwise + column inv FFT (in place) ------
__global__ __launch_bounds__(256) void k_colphase(float2* __restrict__ Wb,
                                                  const float2* __restrict__ FkF,
                                                  const float* __restrict__ fkr,
                                                  const float* __restrict__ fki,
                                                  const float* __restrict__ denq)
{
  __shared__ float2 tw[256];
  __shared__ float2 bufA[4][256];
  __shared__ float2 bufB[4][256];
  __shared__ double2 Ml[2][128];
  int t = threadIdx.x;
  make_tw(tw, t);
  int n = blockIdx.x >> 6;
  int j0 = (blockIdx.x & 63) << 1;
  int w = t >> 6, lane = t & 63;
  int gcw = j0 + (w & 1) + ((w >> 1) << 7);
  float2* Wn = Wb + (size_t)n * HWSZ;
#pragma unroll
  for (int q = 0; q < 4; ++q) { int u = lane + (q << 6); bufA[w][u] = Wn[(size_t)u * NSZ + gcw]; }
  fft256(bufA[w], bufB[w], tw, lane, -1.f);     // bufA = FG columns
  // Fr1 = FkFSTy + alpha*FG  (in place)
#pragma unroll
  for (int c = 0; c < 4; ++c) {
    int u = t;
    int gc = j0 + (c & 1) + ((c >> 1) << 7);
    size_t idx = (size_t)n * HWSZ + (size_t)u * NSZ + gc;
    float2 kf = FkF[idx];
    float2 fg = bufA[c][u];
    bufA[c][u] = make_float2(kf.x + 1e-6f * fg.x, kf.y + 1e-6f * fg.y);
  }
  __syncthreads();
  // M = freq_downsample(Fk*Fr1/FD2) : thread (u0,p), aliases (u0|u0+128) x (p|p+2)
  {
    int u0 = t & 127, p = t >> 7;
    double sx = 0.0, sy = 0.0;
#pragma unroll
    for (int s = 0; s < 4; ++s) {
      int u = u0 + ((s & 1) << 7);
      int c = p + ((s >> 1) << 1);
      int gc = j0 + (c & 1) + ((c >> 1) << 7);
      size_t idx = (size_t)n * HWSZ + (size_t)u * NSZ + gc;
      float2 f1 = bufA[c][u];
      double kr = fkr[idx], ki = fki[idx];
      double fd2 = fdval(tw, u) + fdval(tw, gc) + 1e-8;
      sx += (kr * (double)f1.x - ki * (double)f1.y) / fd2;
      sy += (kr * (double)f1.y + ki * (double)f1.x) / fd2;
    }
    Ml[p][u0] = make_double2(sx * 0.25, sy * 0.25);
  }
  __syncthreads();
  // Fr = (Fr1 - conj(Fk)*M/den) / (alpha*FD2)   (f64 pointwise, in place)
#pragma unroll
  for (int c = 0; c < 4; ++c) {
    int u = t;
    int gc = j0 + (c & 1) + ((c >> 1) << 7);
    size_t idx = (size_t)n * HWSZ + (size_t)u * NSZ + gc;
    float2 f1 = bufA[c][u];
    double2 m = Ml[c & 1][u & 127];
    double den = (double)denq[(size_t)n * 16384 + (size_t)(u & 127) * 128 + (j0 + (c & 1))];
    double kr = fkr[idx], ki = fki[idx];
    // conj(Fk)*M = (kr*Mx + ki*My, kr*My - ki*Mx)
    double px = (kr * m.x + ki * m.y) / den;
    double py = (kr * m.y - ki * m.x) / den;
    double fd2 = fdval(tw, u) + fdval(tw, gc) + 1e-8;
    double sc = 1.0 / (1e-6 * fd2);
    bufA[c][u] = make_float2((float)(((double)f1.x - px) * sc),
                             (float)(((double)f1.y - py) * sc));
  }
  fft256(bufA[w], bufB[w], tw, lane, +1.f);     // inverse along columns (unnormalized)
#pragma unroll
  for (int q = 0; q < 4; ++q) { int u = lane + (q << 6); Wn[(size_t)u * NSZ + gcw] = bufA[w][u]; }
}

// ---------------- K3: row inverse FFT -> x (scaled); final iter also writes pred ------------
__global__ __launch_bounds__(256) void k_rowinv(const float2* __restrict__ Wb,
                                                float* __restrict__ xout,
                                                const float* __restrict__ xold,
                                                float* __restrict__ pred,
                                                float cmom, int isLast)
{
  __shared__ float2 tw[256];
  __shared__ float2 bufA[4][256];
  __shared__ float2 bufB[4][256];
  int t = threadIdx.x;
  make_tw(tw, t);
  int n = blockIdx.x >> 6;
  int r0 = (blockIdx.x & 63) << 2;
  int w = t >> 6, lane = t & 63;
  const float2* src = Wb + (size_t)n * HWSZ + (size_t)(r0 + w) * NSZ;
#pragma unroll
  for (int q = 0; q < 4; ++q) { int j = lane + (q << 6); bufA[w][j] = src[j]; }
  fft256(bufA[w], bufB[w], tw, lane, +1.f);
  size_t base = (size_t)n * HWSZ + (size_t)(r0 + w) * NSZ;
#pragma unroll
  for (int q = 0; q < 4; ++q) {
    int j = lane + (q << 6);
    float v = bufA[w][j].x * (1.0f / 65536.0f);
    xout[base + j] = v;
    if (isLast) pred[base + j] = v + cmom * (v - xold[base + j]);
  }
}

extern "C" void kernel_launch(void* const* d_in, const int* in_sizes, int n_in,
                              void* d_out, int out_size, void* d_ws, size_t ws_size,
                              hipStream_t stream)
{
  (void)in_sizes; (void)n_in; (void)out_size; (void)ws_size;
  const float* STy = (const float*)d_in[0];
  const float* fkr = (const float*)d_in[1];
  const float* fki = (const float*)d_in[2];
  float* out = (float*)d_out;

  char* p = (char*)d_ws;
  const size_t cplx = (size_t)NIMG * HWSZ * sizeof(float2);
  const size_t realb = (size_t)NIMG * HWSZ * sizeof(float);
  float2* Wb  = (float2*)p; p += cplx;
  float2* FkF = (float2*)p; p += cplx;
  float* denq = (float*)p;  p += (size_t)NIMG * 16384 * sizeof(float);
  float* D1a = (float*)p;   p += realb;
  float* D2a = (float*)p;   p += realb;
  float* D1b = (float*)p;   p += realb;
  float* D2b = (float*)p;   p += realb;
  float* x0  = (float*)p;   p += realb;
  float* x1  = (float*)p;   p += realb;

  // D^0 = 0 (ping buffer 0 = D1a,D2a contiguous)
  hipMemsetAsync(D1a, 0, 2 * realb, stream);

  dim3 grid(768), blk(256);
  k_rowfwd_sty<<<grid, blk, 0, stream>>>(STy, Wb);
  k_colsetup<<<grid, blk, 0, stream>>>(Wb, FkF, fkr, fki, denq);
  k_rowinv<<<grid, blk, 0, stream>>>(Wb, x0, x0, out, 0.f, 0);   // x^0 = pred0

  double t_old = 1.0;
  for (int k = 0; k < 50; ++k) {
    float gamp = (k >= 1) ? (float)(0.1 * exp2(-(double)(k - 1) / 50.0)) : 0.f;
    const float* xk = (k & 1) ? x1 : x0;          // x^k
    float* xn = (k & 1) ? x0 : x1;                // x^{k+1}
    const float* D1p = (k & 1) ? D1a : D1b;       // D^{k-1}
    const float* D2p = (k & 1) ? D2a : D2b;
    float* D1w = (k & 1) ? D1b : D1a;             // D^k
    float* D2w = (k & 1) ? D2b : D2a;

    k_spatial_rowfwd<<<grid, blk, 0, stream>>>(xk, D1p, D2p, D1w, D2w, Wb, gamp, (k == 0) ? 1 : 0);
    k_colphase<<<grid, blk, 0, stream>>>(Wb, FkF, fkr, fki, denq);

    double t_new = (1.0 + sqrt(1.0 + 4.0 * t_old * t_old)) * 0.5;
    int isLast = (k == 49) ? 1 : 0;
    float cmom = (float)((t_old - 1.0) / t_new);
    k_rowinv<<<grid, blk, 0, stream>>>(Wb, xn, xk, out, isLast ? cmom : 0.f, isLast);
    t_old = t_new;
  }
}